// Round 1
// baseline (33.718 us; speedup 1.0000x reference)
//
#include <hip/hip_runtime.h>

#define TPB 256

__device__ __forceinline__ float frelu(float v) { return v > 0.f ? v : 0.f; }

// One block per needed output position (38 total).
// Blocks 0..31: position (b=p>>2, h2=(p&3)*20, w2=0), d2 channels {1,161,321},
//               writes head1 row p (2001), head2 row p (801), head3 row p (321).
// Blocks 32..37: head4 positions, single d2 channel, writes 65 outputs.
__global__ __launch_bounds__(TPB) void hyper_kernel(
    const float* __restrict__ x,    // (8,640,640,3)
    const float* __restrict__ k1,   // (5,5,3,32)
    const float* __restrict__ b1,   // (32)
    const float* __restrict__ k2,   // (5,5,32,32)
    const float* __restrict__ b2,   // (32)
    const float* __restrict__ d1k,  // (32,300)
    const float* __restrict__ d1b,  // (300)
    const float* __restrict__ d2k,  // (300,1340)
    const float* __restrict__ d2b,  // (1340)
    const float* __restrict__ w1k, const float* __restrict__ w1b,  // 2001
    const float* __restrict__ w2k, const float* __restrict__ w2b,  // 801
    const float* __restrict__ w3k, const float* __restrict__ w3b,  // 321
    const float* __restrict__ w4k, const float* __restrict__ w4b,  // 65
    float* __restrict__ out)        // 100326
{
    __shared__ float xs[26 * 26 * 3];   // input patch (zero-padded)
    __shared__ float k1s[2400];         // conv1 weights
    __shared__ float p1[6 * 6 * 32];    // pool1 patch (zero = conv2 SAME pad)
    __shared__ float c2[4 * 32];        // conv2-relu at the 4 pool2 taps
    __shared__ float zz[32];            // pool2 output (dense input)
    __shared__ float aa[300];           // d1 output
    __shared__ float yy[3];             // needed d2 channels

    const int p   = blockIdx.x;
    const int tid = threadIdx.x;

    int b, h2, w2, nch, ch0, ch1, ch2;
    if (p < 32) {
        b = p >> 2; h2 = (p & 3) * 20; w2 = 0;
        nch = 3; ch0 = 1; ch1 = 161; ch2 = 321;
    } else {
        const int qb[6] = {0, 1, 2, 4, 5, 6};
        const int qh[6] = {0, 26, 53, 0, 26, 53};
        const int qw[6] = {0, 53, 26, 0, 53, 26};
        const int qc[6] = {481, 491, 501, 481, 491, 501};
        const int q = p - 32;
        b = qb[q]; h2 = qh[q]; w2 = qw[q];
        nch = 1; ch0 = qc[q]; ch1 = 0; ch2 = 0;
    }

    // ---- stage input patch (26x26x3) and conv1 weights into LDS ----
    const int r0 = 8 * h2 - 10;
    const int c0 = 8 * w2 - 10;
    for (int idx = tid; idx < 26 * 26 * 3; idx += TPB) {
        const int ic = idx % 3;
        const int rest = idx / 3;
        const int row = rest / 26, col = rest % 26;
        const int gh = r0 + row, gw = c0 + col;
        float v = 0.f;
        if ((unsigned)gh < 640u && (unsigned)gw < 640u)
            v = x[((b * 640 + gh) * 640 + gw) * 3 + ic];
        xs[idx] = v;
    }
    for (int idx = tid; idx < 2400; idx += TPB) k1s[idx] = k1[idx];
    __syncthreads();

    // ---- pool1 patch: 6x6 positions x 32 channels ----
    // pool1(hp,wp,oc) = max of conv1-relu at rows 4hp..4hp+1, cols 4wp..4wp+1
    for (int idx = tid; idx < 6 * 6 * 32; idx += TPB) {
        const int oc  = idx & 31;
        const int pos = idx >> 5;
        const int hp6 = pos / 6, wp6 = pos % 6;
        const int hp = 2 * h2 - 2 + hp6;
        const int wp = 2 * w2 - 2 + wp6;
        float m = 0.f;  // out-of-range pool1 position => conv2 zero padding
        if ((unsigned)hp < 160u && (unsigned)wp < 160u) {
            const int rbase = 4 * hp6, cbase = 4 * wp6;
            const float bias = b1[oc];
            float a00 = bias, a01 = bias, a10 = bias, a11 = bias;
            for (int dh = 0; dh < 5; ++dh)
                for (int dw = 0; dw < 5; ++dw) {
                    const int lr = rbase + dh, lc = cbase + dw;
                    const float* xp = &xs[(lr * 26 + lc) * 3];
#pragma unroll
                    for (int ic = 0; ic < 3; ++ic) {
                        const float kv = k1s[((dh * 5 + dw) * 3 + ic) * 32 + oc];
                        a00 += xp[ic]           * kv;
                        a01 += xp[3 + ic]       * kv;
                        a10 += xp[26 * 3 + ic]  * kv;
                        a11 += xp[26 * 3 + 3 + ic] * kv;
                    }
                }
            m = frelu(fmaxf(fmaxf(a00, a01), fmaxf(a10, a11)));
        }
        p1[idx] = m;
    }
    __syncthreads();

    // ---- conv2-relu at the 4 pool2 taps ----
    if (tid < 128) {
        const int oc  = tid & 31;
        const int pos = tid >> 5;            // (dy,dx)
        const int dy = pos >> 1, dx = pos & 1;
        float acc = b2[oc];
        for (int dh = 0; dh < 5; ++dh)
            for (int dw = 0; dw < 5; ++dw) {
                const float* pp = &p1[((dy + dh) * 6 + (dx + dw)) * 32];
                const float* kk = &k2[((dh * 5 + dw) * 32) * 32 + oc];
#pragma unroll 8
                for (int ic = 0; ic < 32; ++ic)
                    acc += pp[ic] * kk[ic * 32];
            }
        c2[pos * 32 + oc] = frelu(acc);
    }
    __syncthreads();

    if (tid < 32)
        zz[tid] = fmaxf(fmaxf(c2[tid], c2[32 + tid]),
                        fmaxf(c2[64 + tid], c2[96 + tid]));
    __syncthreads();

    // ---- dense1: 32 -> 300, relu ----
    for (int j = tid; j < 300; j += TPB) {
        float acc = d1b[j];
#pragma unroll 8
        for (int c = 0; c < 32; ++c)
            acc += zz[c] * d1k[c * 300 + j];
        aa[j] = frelu(acc);
    }
    __syncthreads();

    // ---- dense2: only the needed channels (wave-per-channel reduce) ----
    if (tid < 192) {
        const int wv = tid >> 6, lane = tid & 63;
        if (wv < nch) {
            const int ch = (wv == 0) ? ch0 : ((wv == 1) ? ch1 : ch2);
            float s = 0.f;
            for (int j = lane; j < 300; j += 64)
                s += aa[j] * d2k[j * 1340 + ch];
            for (int off = 32; off > 0; off >>= 1)
                s += __shfl_down(s, off);
            if (lane == 0) yy[wv] = frelu(s + d2b[ch]);
        }
    }
    __syncthreads();

    // ---- heads: out = relu(s * k + b) ----
    if (p < 32) {
        const float y1 = yy[0], y2 = yy[1], y3 = yy[2];
        for (int t = tid; t < 2001; t += TPB)
            out[p * 2001 + t] = frelu(y1 * w1k[t] + w1b[t]);
        for (int t = tid; t < 801; t += TPB)
            out[64032 + p * 801 + t] = frelu(y2 * w2k[t] + w2b[t]);
        for (int t = tid; t < 321; t += TPB)
            out[89664 + p * 321 + t] = frelu(y3 * w3k[t] + w3b[t]);
    } else {
        const float y4 = yy[0];
        const int q = p - 32;
        for (int t = tid; t < 65; t += TPB)
            out[99936 + q * 65 + t] = frelu(y4 * w4k[t] + w4b[t]);
    }
}

extern "C" void kernel_launch(void* const* d_in, const int* in_sizes, int n_in,
                              void* d_out, int out_size, void* d_ws, size_t ws_size,
                              hipStream_t stream) {
    (void)in_sizes; (void)n_in; (void)d_ws; (void)ws_size; (void)out_size;
    const float* x   = (const float*)d_in[0];
    const float* k1  = (const float*)d_in[1];
    const float* b1  = (const float*)d_in[2];
    const float* k2  = (const float*)d_in[3];
    const float* b2  = (const float*)d_in[4];
    const float* d1k = (const float*)d_in[5];
    const float* d1b = (const float*)d_in[6];
    const float* d2k = (const float*)d_in[7];
    const float* d2b = (const float*)d_in[8];
    const float* w1k = (const float*)d_in[9];
    const float* w1b = (const float*)d_in[10];
    const float* w2k = (const float*)d_in[11];
    const float* w2b = (const float*)d_in[12];
    const float* w3k = (const float*)d_in[13];
    const float* w3b = (const float*)d_in[14];
    const float* w4k = (const float*)d_in[15];
    const float* w4b = (const float*)d_in[16];

    hyper_kernel<<<38, TPB, 0, stream>>>(
        x, k1, b1, k2, b2, d1k, d1b, d2k, d2b,
        w1k, w1b, w2k, w2b, w3k, w3b, w4k, w4b,
        (float*)d_out);
}

// Round 2
// 19.764 us; speedup vs baseline: 1.7060x; 1.7060x over previous
//
#include <hip/hip_runtime.h>

#define TPB 512

__device__ __forceinline__ float frelu(float v) { return v > 0.f ? v : 0.f; }

// One block per needed output position (38 total).
// Blocks 0..31: (b=p>>2, h2=(p&3)*20, w2=0), d2 channels {1,161,321},
//               writes head1 row p (2001), head2 row p (801), head3 row p (321).
// Blocks 32..37: head4 positions, single d2 channel, writes 65 outputs.
//
// All global loads have data-independent addresses -> issue ALL of them before
// the first barrier (LDS staging + register prefetch); later phases are
// LDS/register-only, so HBM latency is paid exactly once.
__global__ __launch_bounds__(TPB, 1) void hyper_kernel(
    const float* __restrict__ x,    // (8,640,640,3)
    const float* __restrict__ k1,   // (5,5,3,32)
    const float* __restrict__ b1,   // (32)
    const float* __restrict__ k2,   // (5,5,32,32)
    const float* __restrict__ b2,   // (32)
    const float* __restrict__ d1k,  // (32,300)
    const float* __restrict__ d1b,  // (300)
    const float* __restrict__ d2k,  // (300,1340)
    const float* __restrict__ d2b,  // (1340)
    const float* __restrict__ w1k, const float* __restrict__ w1b,  // 2001
    const float* __restrict__ w2k, const float* __restrict__ w2b,  // 801
    const float* __restrict__ w3k, const float* __restrict__ w3b,  // 321
    const float* __restrict__ w4k, const float* __restrict__ w4b,  // 65
    float* __restrict__ out)        // 100326
{
    __shared__ float k2s[25 * 32 * 32];  // 102400 B
    __shared__ float k1s[2400];          // 9600 B
    __shared__ float xs[26 * 26 * 3];    // 8112 B
    __shared__ float p1[36 * 32];        // 4608 B
    __shared__ float c2h[2 * 4 * 32];    // 1024 B
    __shared__ float zz[32];
    __shared__ float aa[300];
    __shared__ float d2cols[3 * 304];    // 3648 B (padded rows)
    __shared__ float d1bs[300];
    __shared__ float b1s[32];
    __shared__ float b2s[32];
    __shared__ float d2bs[3];
    __shared__ float yy[3];

    const int p   = blockIdx.x;
    const int tid = threadIdx.x;

    int b, h2, w2, nch, ch0, ch1, ch2;
    if (p < 32) {
        b = p >> 2; h2 = (p & 3) * 20; w2 = 0;
        nch = 3; ch0 = 1; ch1 = 161; ch2 = 321;
    } else {
        const int qb[6] = {0, 1, 2, 4, 5, 6};
        const int qh[6] = {0, 26, 53, 0, 26, 53};
        const int qw[6] = {0, 53, 26, 0, 53, 26};
        const int qc[6] = {481, 491, 501, 481, 491, 501};
        const int q = p - 32;
        b = qb[q]; h2 = qh[q]; w2 = qw[q];
        nch = 1; ch0 = qc[q]; ch1 = 0; ch2 = 0;
    }

    // ================= phase 0: issue ALL global loads =================

    // d1k columns into registers (thread jD owns dense1 output jD)
    float rd1[32];
    const int jD = tid;
    if (jD < 300) {
#pragma unroll
        for (int c = 0; c < 32; ++c) rd1[c] = d1k[c * 300 + jD];
    }

    // head weight/bias prefetch into registers
    float hk1[4], hb1[4], hk2[2], hb2[2], hk3 = 0.f, hb3 = 0.f, hk4 = 0.f, hb4 = 0.f;
    if (p < 32) {
#pragma unroll
        for (int u = 0; u < 4; ++u) {
            const int i = tid + u * TPB;
            if (i < 2001) { hk1[u] = w1k[i]; hb1[u] = w1b[i]; }
        }
#pragma unroll
        for (int u = 0; u < 2; ++u) {
            const int i = tid + u * TPB;
            if (i < 801) { hk2[u] = w2k[i]; hb2[u] = w2b[i]; }
        }
        if (tid < 321) { hk3 = w3k[tid]; hb3 = w3b[tid]; }
    } else {
        if (tid < 65) { hk4 = w4k[tid]; hb4 = w4b[tid]; }
    }

    // k2 -> LDS (float4 coalesced; 6400 float4)
    {
        const float4* k2v  = (const float4*)k2;
        float4*       k2sv = (float4*)k2s;
        for (int i = tid; i < 6400; i += TPB) k2sv[i] = k2v[i];
    }
    for (int i = tid; i < 2400; i += TPB) k1s[i] = k1[i];

    // input patch (zero-padded)
    const int r0 = 8 * h2 - 10;
    const int c0 = 8 * w2 - 10;
    for (int idx = tid; idx < 26 * 26 * 3; idx += TPB) {
        const int ic = idx % 3;
        const int rest = idx / 3;
        const int row = rest / 26, col = rest % 26;
        const int gh = r0 + row, gw = c0 + col;
        float v = 0.f;
        if ((unsigned)gh < 640u && (unsigned)gw < 640u)
            v = x[((b * 640 + gh) * 640 + gw) * 3 + ic];
        xs[idx] = v;
    }

    // d2k gather columns -> LDS
    for (int t = tid; t < nch * 300; t += TPB) {
        const int wv = t / 300, j = t - wv * 300;
        const int ch = (wv == 0) ? ch0 : ((wv == 1) ? ch1 : ch2);
        d2cols[wv * 304 + j] = d2k[j * 1340 + ch];
    }

    for (int i = tid; i < 300; i += TPB) d1bs[i] = d1b[i];
    if (tid < 32) { b1s[tid] = b1[tid]; b2s[tid] = b2[tid]; }
    if (tid < nch) {
        const int ch = (tid == 0) ? ch0 : ((tid == 1) ? ch1 : ch2);
        d2bs[tid] = d2b[ch];
    }
    __syncthreads();

    // ================= phase 1: conv1-relu-pool1 (6x6x32) =================
    for (int idx = tid; idx < 36 * 32; idx += TPB) {
        const int oc  = idx & 31;
        const int pos = idx >> 5;
        const int hp6 = pos / 6, wp6 = pos % 6;
        const int hp = 2 * h2 - 2 + hp6;
        const int wp = 2 * w2 - 2 + wp6;
        float m = 0.f;  // out-of-range pool1 position => conv2 zero padding
        if ((unsigned)hp < 160u && (unsigned)wp < 160u) {
            const int rbase = 4 * hp6, cbase = 4 * wp6;
            const float bias = b1s[oc];
            float a00 = bias, a01 = bias, a10 = bias, a11 = bias;
            for (int dh = 0; dh < 5; ++dh)
                for (int dw = 0; dw < 5; ++dw) {
                    const int lr = rbase + dh, lc = cbase + dw;
                    const float* xp = &xs[(lr * 26 + lc) * 3];
#pragma unroll
                    for (int ic = 0; ic < 3; ++ic) {
                        const float kv = k1s[((dh * 5 + dw) * 3 + ic) * 32 + oc];
                        a00 += xp[ic]              * kv;
                        a01 += xp[3 + ic]          * kv;
                        a10 += xp[26 * 3 + ic]     * kv;
                        a11 += xp[26 * 3 + 3 + ic] * kv;
                    }
                }
            m = frelu(fmaxf(fmaxf(a00, a01), fmaxf(a10, a11)));
        }
        p1[idx] = m;
    }
    __syncthreads();

    // ============ phase 2: conv2 at 4 pool2 taps (ic split x2) ============
    if (tid < 256) {
        const int oc  = tid & 31;
        const int pos = (tid >> 5) & 3;      // (dy,dx)
        const int icg = tid >> 7;            // 0/1 -> ic 0..15 / 16..31
        const int dy = pos >> 1, dx = pos & 1;
        float acc = 0.f;
        for (int dh = 0; dh < 5; ++dh)
            for (int dw = 0; dw < 5; ++dw) {
                const float* pp = &p1[((dy + dh) * 6 + (dx + dw)) * 32 + icg * 16];
                const float* kk = &k2s[((dh * 5 + dw) * 32 + icg * 16) * 32 + oc];
#pragma unroll
                for (int ic = 0; ic < 16; ++ic)
                    acc += pp[ic] * kk[ic * 32];
            }
        c2h[tid] = acc;  // [icg*128 + pos*32 + oc]
    }
    __syncthreads();

    // ================= phase 3: pool2 -> zz (32) =================
    if (tid < 32) {
        float v0 = frelu(b2s[tid] + c2h[0 * 32 + tid] + c2h[128 + 0 * 32 + tid]);
        float v1 = frelu(b2s[tid] + c2h[1 * 32 + tid] + c2h[128 + 1 * 32 + tid]);
        float v2 = frelu(b2s[tid] + c2h[2 * 32 + tid] + c2h[128 + 2 * 32 + tid]);
        float v3 = frelu(b2s[tid] + c2h[3 * 32 + tid] + c2h[128 + 3 * 32 + tid]);
        zz[tid] = fmaxf(fmaxf(v0, v1), fmaxf(v2, v3));
    }
    __syncthreads();

    // ================= phase 4: dense1 32->300 (register weights) ==========
    if (jD < 300) {
        float acc = d1bs[jD];
#pragma unroll
        for (int c = 0; c < 32; ++c)
            acc += zz[c] * rd1[c];
        aa[jD] = frelu(acc);
    }
    __syncthreads();

    // ============ phase 5: dense2, needed channels only (wave reduce) ======
    if (tid < 64 * nch) {
        const int wv = tid >> 6, lane = tid & 63;
        float s = 0.f;
        for (int j = lane; j < 300; j += 64)
            s += aa[j] * d2cols[wv * 304 + j];
        for (int off = 32; off > 0; off >>= 1)
            s += __shfl_down(s, off);
        if (lane == 0) yy[wv] = frelu(s + d2bs[wv]);
    }
    __syncthreads();

    // ================= phase 6: heads (register weights) =================
    if (p < 32) {
        const float y1 = yy[0], y2 = yy[1], y3 = yy[2];
#pragma unroll
        for (int u = 0; u < 4; ++u) {
            const int i = tid + u * TPB;
            if (i < 2001) out[p * 2001 + i] = frelu(y1 * hk1[u] + hb1[u]);
        }
#pragma unroll
        for (int u = 0; u < 2; ++u) {
            const int i = tid + u * TPB;
            if (i < 801) out[64032 + p * 801 + i] = frelu(y2 * hk2[u] + hb2[u]);
        }
        if (tid < 321) out[89664 + p * 321 + tid] = frelu(y3 * hk3 + hb3);
    } else {
        const float y4 = yy[0];
        if (tid < 65) out[99936 + (p - 32) * 65 + tid] = frelu(y4 * hk4 + hb4);
    }
}

extern "C" void kernel_launch(void* const* d_in, const int* in_sizes, int n_in,
                              void* d_out, int out_size, void* d_ws, size_t ws_size,
                              hipStream_t stream) {
    (void)in_sizes; (void)n_in; (void)d_ws; (void)ws_size; (void)out_size;
    const float* x   = (const float*)d_in[0];
    const float* k1  = (const float*)d_in[1];
    const float* b1  = (const float*)d_in[2];
    const float* k2  = (const float*)d_in[3];
    const float* b2  = (const float*)d_in[4];
    const float* d1k = (const float*)d_in[5];
    const float* d1b = (const float*)d_in[6];
    const float* d2k = (const float*)d_in[7];
    const float* d2b = (const float*)d_in[8];
    const float* w1k = (const float*)d_in[9];
    const float* w1b = (const float*)d_in[10];
    const float* w2k = (const float*)d_in[11];
    const float* w2b = (const float*)d_in[12];
    const float* w3k = (const float*)d_in[13];
    const float* w3b = (const float*)d_in[14];
    const float* w4k = (const float*)d_in[15];
    const float* w4b = (const float*)d_in[16];

    hyper_kernel<<<38, TPB, 0, stream>>>(
        x, k1, b1, k2, b2, d1k, d1b, d2k, d2b,
        w1k, w1b, w2k, w2b, w3k, w3b, w4k, w4b,
        (float*)d_out);
}

// Round 3
// 16.959 us; speedup vs baseline: 1.9882x; 1.1654x over previous
//
#include <hip/hip_runtime.h>

#define TPB 512

__device__ __forceinline__ float frelu(float v) { return v > 0.f ? v : 0.f; }

// One block per needed output position (38 total).
// Blocks 0..31: (b=p>>2, h2=(p&3)*20, w2=0), d2 channels {1,161,321}.
// Blocks 32..37: head4 positions, single d2 channel.
//
// Phase plan (LDS-volume-minimized, staging overlapped):
//  P0: issue all independent global loads (regs + LDS), sync
//  P1: conv1 (threads 0..287, register-blocked 4tap x 4oc)
//      || k2 transpose-stage -> LDS (threads 320..511)
//  P2: conv2 partials (threads 0..255, 1ic x 4oc x 4pos register tile)
//  P3: ic-reduce + bias + relu + pool2 (threads 0..31)
//  P4: dense1 32->300 (register weights)
//  P5: dense2 (wave-per-channel reduce)
//  P6: heads (register weights)
__global__ __launch_bounds__(TPB, 1) void hyper_kernel(
    const float* __restrict__ x,    // (8,640,640,3)
    const float* __restrict__ k1,   // (5,5,3,32)
    const float* __restrict__ b1,   // (32)
    const float* __restrict__ k2,   // (5,5,32,32)
    const float* __restrict__ b2,   // (32)
    const float* __restrict__ d1k,  // (32,300)
    const float* __restrict__ d1b,  // (300)
    const float* __restrict__ d2k,  // (300,1340)
    const float* __restrict__ d2b,  // (1340)
    const float* __restrict__ w1k, const float* __restrict__ w1b,  // 2001
    const float* __restrict__ w2k, const float* __restrict__ w2b,  // 801
    const float* __restrict__ w3k, const float* __restrict__ w3b,  // 321
    const float* __restrict__ w4k, const float* __restrict__ w4b,  // 65
    float* __restrict__ out)        // 100326
{
    // k2 transposed+padded: [tap][oc][ic], row stride 33 (bank-spread)
    __shared__ float k2t[25 * 32 * 33];          // 105600 B
    // arena: xs (2028) + k1s (2400) in P1; reused as part[32][132] in P2/P3
    __shared__ float arena[4428];                // 17712 B
    __shared__ float p1[36 * 32];                // 4608 B
    __shared__ float zz[32];
    __shared__ float aa[300];
    __shared__ float d2cols[3 * 300];
    __shared__ float d1bs[300];
    __shared__ float b1s[32];
    __shared__ float b2s[32];
    __shared__ float d2bs[3];
    __shared__ float yy[3];

    float* const xs   = arena;          // 26*26*3 = 2028
    float* const k1s  = arena + 2028;   // 2400 (16B-aligned: 2028*4=8112)
    float* const part = arena;          // [32][132] after sync2

    const int p   = blockIdx.x;
    const int tid = threadIdx.x;

    int b, h2, w2, nch, ch0, ch1, ch2;
    if (p < 32) {
        b = p >> 2; h2 = (p & 3) * 20; w2 = 0;
        nch = 3; ch0 = 1; ch1 = 161; ch2 = 321;
    } else {
        const int qb[6] = {0, 1, 2, 4, 5, 6};
        const int qh[6] = {0, 26, 53, 0, 26, 53};
        const int qw[6] = {0, 53, 26, 0, 53, 26};
        const int qc[6] = {481, 491, 501, 481, 491, 501};
        const int q = p - 32;
        b = qb[q]; h2 = qh[q]; w2 = qw[q];
        nch = 1; ch0 = qc[q]; ch1 = 0; ch2 = 0;
    }

    // ================= P0: issue all independent global loads =============
    float rd1[32];
    if (tid < 300) {
#pragma unroll
        for (int c = 0; c < 32; ++c) rd1[c] = d1k[c * 300 + tid];
    }

    float hk1[4], hb1[4], hk2[2], hb2[2], hk3 = 0.f, hb3 = 0.f, hk4 = 0.f, hb4 = 0.f;
    if (p < 32) {
#pragma unroll
        for (int u = 0; u < 4; ++u) {
            const int i = tid + u * TPB;
            if (i < 2001) { hk1[u] = w1k[i]; hb1[u] = w1b[i]; }
        }
#pragma unroll
        for (int u = 0; u < 2; ++u) {
            const int i = tid + u * TPB;
            if (i < 801) { hk2[u] = w2k[i]; hb2[u] = w2b[i]; }
        }
        if (tid < 321) { hk3 = w3k[tid]; hb3 = w3b[tid]; }
    } else {
        if (tid < 65) { hk4 = w4k[tid]; hb4 = w4b[tid]; }
    }

    // input patch (zero-padded), k1, d2 gather columns, small vectors
    const int r0 = 8 * h2 - 10;
    const int c0 = 8 * w2 - 10;
    for (int idx = tid; idx < 26 * 26 * 3; idx += TPB) {
        const int ic = idx % 3;
        const int rest = idx / 3;
        const int row = rest / 26, col = rest % 26;
        const int gh = r0 + row, gw = c0 + col;
        float v = 0.f;
        if ((unsigned)gh < 640u && (unsigned)gw < 640u)
            v = x[((b * 640 + gh) * 640 + gw) * 3 + ic];
        xs[idx] = v;
    }
    for (int i = tid; i < 2400; i += TPB) k1s[i] = k1[i];
    for (int t = tid; t < nch * 300; t += TPB) {
        const int wv = t / 300, j = t - wv * 300;
        const int ch = (wv == 0) ? ch0 : ((wv == 1) ? ch1 : ch2);
        d2cols[wv * 300 + j] = d2k[j * 1340 + ch];
    }
    for (int i = tid; i < 300; i += TPB) d1bs[i] = d1b[i];
    if (tid < 32) { b1s[tid] = b1[tid]; b2s[tid] = b2[tid]; }
    if (tid < nch) {
        const int ch = (tid == 0) ? ch0 : ((tid == 1) ? ch1 : ch2);
        d2bs[tid] = d2b[ch];
    }
    __syncthreads();   // sync1 — one HBM round trip for everything above

    // ===== P1: conv1 (0..287)  ||  k2 transpose-stage (320..511) ==========
    if (tid < 288) {
        const int pos = tid >> 3;        // 0..35 pool1 position
        const int ocg = tid & 7;         // 4 oc per thread
        const int hp6 = pos / 6, wp6 = pos % 6;
        const int hp = 2 * h2 - 2 + hp6;
        const int wp = 2 * w2 - 2 + wp6;
        float r00 = 0.f, r01 = 0.f, r10 = 0.f, r11 = 0.f;  // placeholder
        float acc[4][4];
        const bool ok = ((unsigned)hp < 160u && (unsigned)wp < 160u);
        if (ok) {
            const float bias0 = b1s[ocg * 4 + 0];
            const float bias1 = b1s[ocg * 4 + 1];
            const float bias2 = b1s[ocg * 4 + 2];
            const float bias3 = b1s[ocg * 4 + 3];
#pragma unroll
            for (int t4 = 0; t4 < 4; ++t4) {
                acc[t4][0] = bias0; acc[t4][1] = bias1;
                acc[t4][2] = bias2; acc[t4][3] = bias3;
            }
            const int rbase = 4 * hp6, cbase = 4 * wp6;
            for (int dh = 0; dh < 5; ++dh)
                for (int dw = 0; dw < 5; ++dw) {
#pragma unroll
                    for (int ic = 0; ic < 3; ++ic) {
                        const float4 kv = *(const float4*)&k1s[(((dh * 5 + dw) * 3 + ic) << 5) + (ocg << 2)];
                        const float* xp = &xs[((rbase + dh) * 26 + cbase + dw) * 3 + ic];
                        const float x00 = xp[0];
                        const float x01 = xp[3];
                        const float x10 = xp[78];
                        const float x11 = xp[81];
                        acc[0][0] += x00 * kv.x; acc[0][1] += x00 * kv.y;
                        acc[0][2] += x00 * kv.z; acc[0][3] += x00 * kv.w;
                        acc[1][0] += x01 * kv.x; acc[1][1] += x01 * kv.y;
                        acc[1][2] += x01 * kv.z; acc[1][3] += x01 * kv.w;
                        acc[2][0] += x10 * kv.x; acc[2][1] += x10 * kv.y;
                        acc[2][2] += x10 * kv.z; acc[2][3] += x10 * kv.w;
                        acc[3][0] += x11 * kv.x; acc[3][1] += x11 * kv.y;
                        acc[3][2] += x11 * kv.z; acc[3][3] += x11 * kv.w;
                    }
                }
            r00 = frelu(fmaxf(fmaxf(acc[0][0], acc[1][0]), fmaxf(acc[2][0], acc[3][0])));
            r01 = frelu(fmaxf(fmaxf(acc[0][1], acc[1][1]), fmaxf(acc[2][1], acc[3][1])));
            r10 = frelu(fmaxf(fmaxf(acc[0][2], acc[1][2]), fmaxf(acc[2][2], acc[3][2])));
            r11 = frelu(fmaxf(fmaxf(acc[0][3], acc[1][3]), fmaxf(acc[2][3], acc[3][3])));
        }
        float* pp = &p1[pos * 32 + ocg * 4];
        pp[0] = r00; pp[1] = r01; pp[2] = r10; pp[3] = r11;
    } else if (tid >= 320) {
        // transpose-stage k2 (5,5,32,32)=[tap][ic][oc] -> k2t[tap][oc][ic+pad]
        const float4* k2v = (const float4*)k2;
        for (int i = tid - 320; i < 6400; i += 192) {
            const float4 v = k2v[i];
            const int tap = i >> 8;
            const int ic  = (i >> 3) & 31;
            const int oc0 = (i & 7) * 4;
            float* dst = &k2t[tap * 1056 + oc0 * 33 + ic];
            dst[0]  = v.x;
            dst[33] = v.y;
            dst[66] = v.z;
            dst[99] = v.w;
        }
    }
    __syncthreads();   // sync2 — p1 + k2t ready; xs/k1s dead (arena -> part)

    // ===== P2: conv2 partials: thread = (ic, ocg), tile 4pos x 4oc ========
    if (tid < 256) {
        const int ic  = tid >> 3;
        const int ocg = tid & 7;
        float acc[4][4];
#pragma unroll
        for (int q = 0; q < 4; ++q) { acc[q][0] = acc[q][1] = acc[q][2] = acc[q][3] = 0.f; }
        for (int dh = 0; dh < 5; ++dh)
            for (int dw = 0; dw < 5; ++dw) {
                const int tap = dh * 5 + dw;
                float pv[4];
#pragma unroll
                for (int pos = 0; pos < 4; ++pos) {
                    const int dy = pos >> 1, dx = pos & 1;
                    pv[pos] = p1[((dy + dh) * 6 + (dx + dw)) * 32 + ic];
                }
                const float* kb = &k2t[tap * 1056 + (ocg * 4) * 33 + ic];
#pragma unroll
                for (int o = 0; o < 4; ++o) {
                    const float kv = kb[o * 33];
#pragma unroll
                    for (int pos = 0; pos < 4; ++pos)
                        acc[pos][o] += pv[pos] * kv;
                }
            }
#pragma unroll
        for (int pos = 0; pos < 4; ++pos)
#pragma unroll
            for (int o = 0; o < 4; ++o)
                part[ic * 132 + pos * 32 + ocg * 4 + o] = acc[pos][o];
    }
    __syncthreads();   // sync3

    // ===== P3: ic-reduce + bias + relu + pool2 -> zz =======================
    if (tid < 32) {
        const float bias = b2s[tid];
        float s0 = bias, s1 = bias, s2 = bias, s3 = bias;
        for (int g = 0; g < 32; ++g) {
            const float* pr = &part[g * 132 + tid];
            s0 += pr[0]; s1 += pr[32]; s2 += pr[64]; s3 += pr[96];
        }
        zz[tid] = fmaxf(fmaxf(frelu(s0), frelu(s1)), fmaxf(frelu(s2), frelu(s3)));
    }
    __syncthreads();   // sync4

    // ===== P4: dense1 32->300 (register weights) ===========================
    if (tid < 300) {
        float acc = d1bs[tid];
#pragma unroll
        for (int c = 0; c < 32; ++c)
            acc += zz[c] * rd1[c];
        aa[tid] = frelu(acc);
    }
    __syncthreads();   // sync5

    // ===== P5: dense2, needed channels only (wave reduce) ==================
    if (tid < 64 * nch) {
        const int wv = tid >> 6, lane = tid & 63;
        float s = 0.f;
        for (int j = lane; j < 300; j += 64)
            s += aa[j] * d2cols[wv * 300 + j];
        for (int off = 32; off > 0; off >>= 1)
            s += __shfl_down(s, off);
        if (lane == 0) yy[wv] = frelu(s + d2bs[wv]);
    }
    __syncthreads();   // sync6

    // ===== P6: heads (register weights) ====================================
    if (p < 32) {
        const float y1 = yy[0], y2 = yy[1], y3 = yy[2];
#pragma unroll
        for (int u = 0; u < 4; ++u) {
            const int i = tid + u * TPB;
            if (i < 2001) out[p * 2001 + i] = frelu(y1 * hk1[u] + hb1[u]);
        }
#pragma unroll
        for (int u = 0; u < 2; ++u) {
            const int i = tid + u * TPB;
            if (i < 801) out[64032 + p * 801 + i] = frelu(y2 * hk2[u] + hb2[u]);
        }
        if (tid < 321) out[89664 + p * 321 + tid] = frelu(y3 * hk3 + hb3);
    } else {
        const float y4 = yy[0];
        if (tid < 65) out[99936 + (p - 32) * 65 + tid] = frelu(y4 * hk4 + hb4);
    }
}

extern "C" void kernel_launch(void* const* d_in, const int* in_sizes, int n_in,
                              void* d_out, int out_size, void* d_ws, size_t ws_size,
                              hipStream_t stream) {
    (void)in_sizes; (void)n_in; (void)d_ws; (void)ws_size; (void)out_size;
    const float* x   = (const float*)d_in[0];
    const float* k1  = (const float*)d_in[1];
    const float* b1  = (const float*)d_in[2];
    const float* k2  = (const float*)d_in[3];
    const float* b2  = (const float*)d_in[4];
    const float* d1k = (const float*)d_in[5];
    const float* d1b = (const float*)d_in[6];
    const float* d2k = (const float*)d_in[7];
    const float* d2b = (const float*)d_in[8];
    const float* w1k = (const float*)d_in[9];
    const float* w1b = (const float*)d_in[10];
    const float* w2k = (const float*)d_in[11];
    const float* w2b = (const float*)d_in[12];
    const float* w3k = (const float*)d_in[13];
    const float* w3b = (const float*)d_in[14];
    const float* w4k = (const float*)d_in[15];
    const float* w4b = (const float*)d_in[16];

    hyper_kernel<<<38, TPB, 0, stream>>>(
        x, k1, b1, k2, b2, d1k, d1b, d2k, d2b,
        w1k, w1b, w2k, w2b, w3k, w3b, w4k, w4b,
        (float*)d_out);
}

// Round 4
// 16.367 us; speedup vs baseline: 2.0601x; 1.0362x over previous
//
#include <hip/hip_runtime.h>

#define TPB 512

__device__ __forceinline__ float frelu(float v) { return v > 0.f ? v : 0.f; }

// One block per needed output position (38 total).
// Blocks 0..31: (b=p>>2, h2=(p&3)*20, w2=0), d2 channels {1,161,321}.
// Blocks 32..37: head4 positions, single d2 channel.
//
// Phase plan:
//  P0: issue all independent global loads (regs + LDS), sync
//  P1: conv1 (threads 0..287, register-blocked 4tap x 4oc)
//  P2: conv2 partials (threads 0..255, 1ic x 4oc x 4pos), k2 read from
//      GLOBAL (L2) with coalesced float4 — no LDS staging of k2 at all
//  P3: ic-reduce + bias + relu + pool2 (128 threads + shfl_xor max)
//  P4: dense1 32->300 (register weights)
//  P5: dense2 (wave-per-channel reduce)
//  P6: heads (register weights)
__global__ __launch_bounds__(TPB, 1) void hyper_kernel(
    const float* __restrict__ x,    // (8,640,640,3)
    const float* __restrict__ k1,   // (5,5,3,32)
    const float* __restrict__ b1,   // (32)
    const float* __restrict__ k2,   // (5,5,32,32)
    const float* __restrict__ b2,   // (32)
    const float* __restrict__ d1k,  // (32,300)
    const float* __restrict__ d1b,  // (300)
    const float* __restrict__ d2k,  // (300,1340)
    const float* __restrict__ d2b,  // (1340)
    const float* __restrict__ w1k, const float* __restrict__ w1b,  // 2001
    const float* __restrict__ w2k, const float* __restrict__ w2b,  // 801
    const float* __restrict__ w3k, const float* __restrict__ w3b,  // 321
    const float* __restrict__ w4k, const float* __restrict__ w4b,  // 65
    float* __restrict__ out)        // 100326
{
    __shared__ float xs[26 * 26 * 3];    // 8112 B
    __shared__ float k1s[2400];          // 9600 B
    __shared__ float p1[36 * 32];        // 4608 B
    __shared__ float part[32 * 132];     // 16896 B  [ic][pos*32+oc], pad 4
    __shared__ float zz[32];
    __shared__ float aa[300];
    __shared__ float d2cols[3 * 300];
    __shared__ float d1bs[300];
    __shared__ float b1s[32];
    __shared__ float b2s[32];
    __shared__ float d2bs[3];
    __shared__ float yy[3];

    const int p   = blockIdx.x;
    const int tid = threadIdx.x;

    int b, h2, w2, nch, ch0, ch1, ch2;
    if (p < 32) {
        b = p >> 2; h2 = (p & 3) * 20; w2 = 0;
        nch = 3; ch0 = 1; ch1 = 161; ch2 = 321;
    } else {
        const int qb[6] = {0, 1, 2, 4, 5, 6};
        const int qh[6] = {0, 26, 53, 0, 26, 53};
        const int qw[6] = {0, 53, 26, 0, 53, 26};
        const int qc[6] = {481, 491, 501, 481, 491, 501};
        const int q = p - 32;
        b = qb[q]; h2 = qh[q]; w2 = qw[q];
        nch = 1; ch0 = qc[q]; ch1 = 0; ch2 = 0;
    }

    // ================= P0: issue all independent global loads =============
    float rd1[32];
    if (tid < 300) {
#pragma unroll
        for (int c = 0; c < 32; ++c) rd1[c] = d1k[c * 300 + tid];
    }

    float hk1[4], hb1[4], hk2[2], hb2[2], hk3 = 0.f, hb3 = 0.f, hk4 = 0.f, hb4 = 0.f;
    if (p < 32) {
#pragma unroll
        for (int u = 0; u < 4; ++u) {
            const int i = tid + u * TPB;
            if (i < 2001) { hk1[u] = w1k[i]; hb1[u] = w1b[i]; }
        }
#pragma unroll
        for (int u = 0; u < 2; ++u) {
            const int i = tid + u * TPB;
            if (i < 801) { hk2[u] = w2k[i]; hb2[u] = w2b[i]; }
        }
        if (tid < 321) { hk3 = w3k[tid]; hb3 = w3b[tid]; }
    } else {
        if (tid < 65) { hk4 = w4k[tid]; hb4 = w4b[tid]; }
    }

    // input patch (zero-padded), k1, d2 gather columns, small vectors
    const int r0 = 8 * h2 - 10;
    const int c0 = 8 * w2 - 10;
    for (int idx = tid; idx < 26 * 26 * 3; idx += TPB) {
        const int ic = idx % 3;
        const int rest = idx / 3;
        const int row = rest / 26, col = rest % 26;
        const int gh = r0 + row, gw = c0 + col;
        float v = 0.f;
        if ((unsigned)gh < 640u && (unsigned)gw < 640u)
            v = x[((b * 640 + gh) * 640 + gw) * 3 + ic];
        xs[idx] = v;
    }
    for (int i = tid; i < 2400; i += TPB) k1s[i] = k1[i];
    for (int t = tid; t < nch * 300; t += TPB) {
        const int wv = t / 300, j = t - wv * 300;
        const int ch = (wv == 0) ? ch0 : ((wv == 1) ? ch1 : ch2);
        d2cols[wv * 300 + j] = d2k[j * 1340 + ch];
    }
    for (int i = tid; i < 300; i += TPB) d1bs[i] = d1b[i];
    if (tid < 32) { b1s[tid] = b1[tid]; b2s[tid] = b2[tid]; }
    if (tid < nch) {
        const int ch = (tid == 0) ? ch0 : ((tid == 1) ? ch1 : ch2);
        d2bs[tid] = d2b[ch];
    }
    __syncthreads();   // sync1 — one HBM round trip for everything above

    // ===== P1: conv1 (threads 0..287, 4tap x 4oc register tile) ===========
    if (tid < 288) {
        const int pos = tid >> 3;        // 0..35 pool1 position
        const int ocg = tid & 7;         // 4 oc per thread
        const int hp6 = pos / 6, wp6 = pos % 6;
        const int hp = 2 * h2 - 2 + hp6;
        const int wp = 2 * w2 - 2 + wp6;
        float r00 = 0.f, r01 = 0.f, r10 = 0.f, r11 = 0.f;
        float acc[4][4];
        const bool ok = ((unsigned)hp < 160u && (unsigned)wp < 160u);
        if (ok) {
            const float bias0 = b1s[ocg * 4 + 0];
            const float bias1 = b1s[ocg * 4 + 1];
            const float bias2 = b1s[ocg * 4 + 2];
            const float bias3 = b1s[ocg * 4 + 3];
#pragma unroll
            for (int t4 = 0; t4 < 4; ++t4) {
                acc[t4][0] = bias0; acc[t4][1] = bias1;
                acc[t4][2] = bias2; acc[t4][3] = bias3;
            }
            const int rbase = 4 * hp6, cbase = 4 * wp6;
            for (int dh = 0; dh < 5; ++dh)
                for (int dw = 0; dw < 5; ++dw) {
#pragma unroll
                    for (int ic = 0; ic < 3; ++ic) {
                        const float4 kv = *(const float4*)&k1s[(((dh * 5 + dw) * 3 + ic) << 5) + (ocg << 2)];
                        const float* xp = &xs[((rbase + dh) * 26 + cbase + dw) * 3 + ic];
                        const float x00 = xp[0];
                        const float x01 = xp[3];
                        const float x10 = xp[78];
                        const float x11 = xp[81];
                        acc[0][0] += x00 * kv.x; acc[0][1] += x00 * kv.y;
                        acc[0][2] += x00 * kv.z; acc[0][3] += x00 * kv.w;
                        acc[1][0] += x01 * kv.x; acc[1][1] += x01 * kv.y;
                        acc[1][2] += x01 * kv.z; acc[1][3] += x01 * kv.w;
                        acc[2][0] += x10 * kv.x; acc[2][1] += x10 * kv.y;
                        acc[2][2] += x10 * kv.z; acc[2][3] += x10 * kv.w;
                        acc[3][0] += x11 * kv.x; acc[3][1] += x11 * kv.y;
                        acc[3][2] += x11 * kv.z; acc[3][3] += x11 * kv.w;
                    }
                }
            r00 = frelu(fmaxf(fmaxf(acc[0][0], acc[1][0]), fmaxf(acc[2][0], acc[3][0])));
            r01 = frelu(fmaxf(fmaxf(acc[0][1], acc[1][1]), fmaxf(acc[2][1], acc[3][1])));
            r10 = frelu(fmaxf(fmaxf(acc[0][2], acc[1][2]), fmaxf(acc[2][2], acc[3][2])));
            r11 = frelu(fmaxf(fmaxf(acc[0][3], acc[1][3]), fmaxf(acc[2][3], acc[3][3])));
        }
        float* pp = &p1[pos * 32 + ocg * 4];
        pp[0] = r00; pp[1] = r01; pp[2] = r10; pp[3] = r11;
    }
    __syncthreads();   // sync2 — p1 ready

    // ===== P2: conv2 partials, k2 from GLOBAL (coalesced float4) ==========
    if (tid < 256) {
        const int ic  = tid >> 3;
        const int ocg = tid & 7;
        float acc[4][4];
#pragma unroll
        for (int q = 0; q < 4; ++q) { acc[q][0] = acc[q][1] = acc[q][2] = acc[q][3] = 0.f; }
        const float4* k2v = (const float4*)(k2 + ic * 32 + ocg * 4);
#pragma unroll
        for (int dh = 0; dh < 5; ++dh)
#pragma unroll
            for (int dw = 0; dw < 5; ++dw) {
                const int tap = dh * 5 + dw;
                const float4 kv = k2v[tap * 256];   // k2[tap][ic][ocg*4..+3]
                float pv[4];
#pragma unroll
                for (int pos = 0; pos < 4; ++pos) {
                    const int dy = pos >> 1, dx = pos & 1;
                    pv[pos] = p1[((dy + dh) * 6 + (dx + dw)) * 32 + ic];
                }
#pragma unroll
                for (int pos = 0; pos < 4; ++pos) {
                    acc[pos][0] += pv[pos] * kv.x;
                    acc[pos][1] += pv[pos] * kv.y;
                    acc[pos][2] += pv[pos] * kv.z;
                    acc[pos][3] += pv[pos] * kv.w;
                }
            }
#pragma unroll
        for (int pos = 0; pos < 4; ++pos)
#pragma unroll
            for (int o = 0; o < 4; ++o)
                part[ic * 132 + pos * 32 + ocg * 4 + o] = acc[pos][o];
    }
    __syncthreads();   // sync3

    // ===== P3: ic-reduce + bias + relu + pool2 (128 thr + shfl max) =======
    if (tid < 128) {
        const int oc  = tid >> 2;        // lane bits 2..6
        const int pos = tid & 3;         // lane bits 0..1 (shfl_xor stays in-wave)
        float s = b2s[oc];
        for (int ic = 0; ic < 32; ++ic)
            s += part[ic * 132 + pos * 32 + oc];
        float v = frelu(s);
        v = fmaxf(v, __shfl_xor(v, 1));
        v = fmaxf(v, __shfl_xor(v, 2));
        if (pos == 0) zz[oc] = v;
    }
    __syncthreads();   // sync4

    // ===== P4: dense1 32->300 (register weights) ===========================
    if (tid < 300) {
        float acc = d1bs[tid];
#pragma unroll
        for (int c = 0; c < 32; ++c)
            acc += zz[c] * rd1[c];
        aa[tid] = frelu(acc);
    }
    __syncthreads();   // sync5

    // ===== P5: dense2, needed channels only (wave reduce) ==================
    if (tid < 64 * nch) {
        const int wv = tid >> 6, lane = tid & 63;
        float s = 0.f;
        for (int j = lane; j < 300; j += 64)
            s += aa[j] * d2cols[wv * 300 + j];
        for (int off = 32; off > 0; off >>= 1)
            s += __shfl_down(s, off);
        if (lane == 0) yy[wv] = frelu(s + d2bs[wv]);
    }
    __syncthreads();   // sync6

    // ===== P6: heads (register weights) ====================================
    if (p < 32) {
        const float y1 = yy[0], y2 = yy[1], y3 = yy[2];
#pragma unroll
        for (int u = 0; u < 4; ++u) {
            const int i = tid + u * TPB;
            if (i < 2001) out[p * 2001 + i] = frelu(y1 * hk1[u] + hb1[u]);
        }
#pragma unroll
        for (int u = 0; u < 2; ++u) {
            const int i = tid + u * TPB;
            if (i < 801) out[64032 + p * 801 + i] = frelu(y2 * hk2[u] + hb2[u]);
        }
        if (tid < 321) out[89664 + p * 321 + tid] = frelu(y3 * hk3 + hb3);
    } else {
        const float y4 = yy[0];
        if (tid < 65) out[99936 + (p - 32) * 65 + tid] = frelu(y4 * hk4 + hb4);
    }
}

extern "C" void kernel_launch(void* const* d_in, const int* in_sizes, int n_in,
                              void* d_out, int out_size, void* d_ws, size_t ws_size,
                              hipStream_t stream) {
    (void)in_sizes; (void)n_in; (void)d_ws; (void)ws_size; (void)out_size;
    const float* x   = (const float*)d_in[0];
    const float* k1  = (const float*)d_in[1];
    const float* b1  = (const float*)d_in[2];
    const float* k2  = (const float*)d_in[3];
    const float* b2  = (const float*)d_in[4];
    const float* d1k = (const float*)d_in[5];
    const float* d1b = (const float*)d_in[6];
    const float* d2k = (const float*)d_in[7];
    const float* d2b = (const float*)d_in[8];
    const float* w1k = (const float*)d_in[9];
    const float* w1b = (const float*)d_in[10];
    const float* w2k = (const float*)d_in[11];
    const float* w2b = (const float*)d_in[12];
    const float* w3k = (const float*)d_in[13];
    const float* w3b = (const float*)d_in[14];
    const float* w4k = (const float*)d_in[15];
    const float* w4b = (const float*)d_in[16];

    hyper_kernel<<<38, TPB, 0, stream>>>(
        x, k1, b1, k2, b2, d1k, d1b, d2k, d2b,
        w1k, w1b, w2k, w2b, w3k, w3b, w4k, w4b,
        (float*)d_out);
}

// Round 5
// 14.870 us; speedup vs baseline: 2.2675x; 1.1006x over previous
//
#include <hip/hip_runtime.h>

#define TPB 512

__device__ __forceinline__ float frelu(float v) { return v > 0.f ? v : 0.f; }

// One block per needed output position (38 total).
// Blocks 0..31: (b=p>>2, h2=(p&3)*20, w2=0), d2 channels {1,161,321}.
// Blocks 32..37: head4 positions, single d2 channel.
//
//  P0: issue ALL global loads (regs + LDS), incl. k2 -> regs of thr 256-511
//  P1: conv1 (threads 0..287, planar-x register-blocked 4tap x 4oc)
//  P2: conv2 partials (threads 256..511, k2 already in registers)
//  P3: ic-reduce + bias + relu + pool2 (threads 0..127 + shfl_xor max)
//  P4: dense1 32->300 (register weights)
//  P5: dense2 (wave-per-channel reduce, d2 weights in registers)
//  P6: heads (register weights)
__global__ __launch_bounds__(TPB, 1) void hyper_kernel(
    const float* __restrict__ x,    // (8,640,640,3)
    const float* __restrict__ k1,   // (5,5,3,32)
    const float* __restrict__ b1,   // (32)
    const float* __restrict__ k2,   // (5,5,32,32)
    const float* __restrict__ b2,   // (32)
    const float* __restrict__ d1k,  // (32,300)
    const float* __restrict__ d1b,  // (300)
    const float* __restrict__ d2k,  // (300,1340)
    const float* __restrict__ d2b,  // (1340)
    const float* __restrict__ w1k, const float* __restrict__ w1b,  // 2001
    const float* __restrict__ w2k, const float* __restrict__ w2b,  // 801
    const float* __restrict__ w3k, const float* __restrict__ w3b,  // 321
    const float* __restrict__ w4k, const float* __restrict__ w4b,  // 65
    float* __restrict__ out)        // 100326
{
    __shared__ float xs[3 * 676];        // channel-planar x patch [ic][26][26]
    __shared__ float k1s[2400];
    __shared__ float p1[36 * 32];
    __shared__ float part[32 * 132];     // [ic][pos*32+oc], pad 4
    __shared__ float zz[32];
    __shared__ float aa[300];
    __shared__ float yy[3];

    const int p   = blockIdx.x;
    const int tid = threadIdx.x;

    int b, h2, w2, nch, ch0, ch1, ch2;
    if (p < 32) {
        b = p >> 2; h2 = (p & 3) * 20; w2 = 0;
        nch = 3; ch0 = 1; ch1 = 161; ch2 = 321;
    } else {
        const int qb[6] = {0, 1, 2, 4, 5, 6};
        const int qh[6] = {0, 26, 53, 0, 26, 53};
        const int qw[6] = {0, 53, 26, 0, 53, 26};
        const int qc[6] = {481, 491, 501, 481, 491, 501};
        const int q = p - 32;
        b = qb[q]; h2 = qh[q]; w2 = qw[q];
        nch = 1; ch0 = qc[q]; ch1 = 0; ch2 = 0;
    }

    // ================= P0: issue ALL independent global loads =============
    // dense1 weights+bias (thread j owns output j)
    float rd1[32];
    float d1breg = 0.f;
    if (tid < 300) {
#pragma unroll
        for (int c = 0; c < 32; ++c) rd1[c] = d1k[c * 300 + tid];
        d1breg = d1b[tid];
    }

    // conv1 bias (4 oc per conv1 thread)
    float4 b1reg = make_float4(0.f, 0.f, 0.f, 0.f);
    if (tid < 288) b1reg = *(const float4*)&b1[(tid & 7) * 4];

    // conv2 bias (P3 threads)
    float b2reg = (tid < 128) ? b2[tid >> 2] : 0.f;

    // dense2 gather columns + bias -> P5 thread registers
    float d2reg[5] = {0.f, 0.f, 0.f, 0.f, 0.f};
    float d2breg = 0.f;
    if (tid < 192) {
        const int wv = tid >> 6;
        if (wv < nch) {
            const int ch = (wv == 0) ? ch0 : ((wv == 1) ? ch1 : ch2);
#pragma unroll
            for (int u = 0; u < 5; ++u) {
                const int j = (tid & 63) + 64 * u;
                if (j < 300) d2reg[u] = d2k[j * 1340 + ch];
            }
            d2breg = d2b[ch];
        }
    }

    // k2 -> registers of the P2 threads (256..511): 25 float4 each
    float4 kreg[25];
    if (tid >= 256) {
        const int t = tid - 256;
        const float4* k2v = (const float4*)k2 + (t >> 3) * 8 + (t & 7);
#pragma unroll
        for (int tap = 0; tap < 25; ++tap) kreg[tap] = k2v[tap * 256];
    }

    // head weights/biases -> registers
    float hk1[4], hb1[4], hk2[2], hb2[2], hk3 = 0.f, hb3 = 0.f, hk4 = 0.f, hb4 = 0.f;
    if (p < 32) {
#pragma unroll
        for (int u = 0; u < 4; ++u) {
            const int i = tid + u * TPB;
            if (i < 2001) { hk1[u] = w1k[i]; hb1[u] = w1b[i]; }
        }
#pragma unroll
        for (int u = 0; u < 2; ++u) {
            const int i = tid + u * TPB;
            if (i < 801) { hk2[u] = w2k[i]; hb2[u] = w2b[i]; }
        }
        if (tid < 321) { hk3 = w3k[tid]; hb3 = w3b[tid]; }
    } else {
        if (tid < 65) { hk4 = w4k[tid]; hb4 = w4b[tid]; }
    }

    // x patch -> LDS, channel-planar (zero-padded)
    const int r0 = 8 * h2 - 10;
    const int c0 = 8 * w2 - 10;
    for (int idx = tid; idx < 3 * 676; idx += TPB) {
        const int ic  = idx / 676;
        const int rem = idx - ic * 676;
        const int row = rem / 26, col = rem - (rem / 26) * 26;
        const int gh = r0 + row, gw = c0 + col;
        float v = 0.f;
        if ((unsigned)gh < 640u && (unsigned)gw < 640u)
            v = x[((b * 640 + gh) * 640 + gw) * 3 + ic];
        xs[idx] = v;
    }
    for (int i = tid; i < 2400; i += TPB) k1s[i] = k1[i];
    __syncthreads();   // sync1 — one round trip for everything above

    // ===== P1: conv1 (threads 0..287, planar x, 4tap x 4oc tile) ==========
    if (tid < 288) {
        const int pos = tid >> 3;        // 0..35 pool1 position
        const int ocg = tid & 7;         // 4 oc per thread
        const int hp6 = pos / 6, wp6 = pos - hp6 * 6;
        const int hp = 2 * h2 - 2 + hp6;
        const int wp = 2 * w2 - 2 + wp6;
        float r00 = 0.f, r01 = 0.f, r10 = 0.f, r11 = 0.f;
        if ((unsigned)hp < 160u && (unsigned)wp < 160u) {
            float acc[4][4];
#pragma unroll
            for (int t4 = 0; t4 < 4; ++t4) {
                acc[t4][0] = b1reg.x; acc[t4][1] = b1reg.y;
                acc[t4][2] = b1reg.z; acc[t4][3] = b1reg.w;
            }
            const int rbase = 4 * hp6, cbase = 4 * wp6;
#pragma unroll
            for (int dh = 0; dh < 5; ++dh) {
#pragma unroll
                for (int ic = 0; ic < 3; ++ic) {
                    const float* rp0 = &xs[ic * 676 + (rbase + dh) * 26 + cbase];
                    const float2 a0 = *(const float2*)(rp0);
                    const float2 a2 = *(const float2*)(rp0 + 2);
                    const float2 a4 = *(const float2*)(rp0 + 4);
                    const float2 c0_ = *(const float2*)(rp0 + 26);
                    const float2 c2_ = *(const float2*)(rp0 + 28);
                    const float2 c4_ = *(const float2*)(rp0 + 30);
                    const float xr0[6] = {a0.x, a0.y, a2.x, a2.y, a4.x, a4.y};
                    const float xr1[6] = {c0_.x, c0_.y, c2_.x, c2_.y, c4_.x, c4_.y};
#pragma unroll
                    for (int dw = 0; dw < 5; ++dw) {
                        const float4 kv = *(const float4*)&k1s[(((dh * 5 + dw) * 3 + ic) << 5) + (ocg << 2)];
                        const float x00 = xr0[dw], x01 = xr0[dw + 1];
                        const float x10 = xr1[dw], x11 = xr1[dw + 1];
                        acc[0][0] += x00 * kv.x; acc[0][1] += x00 * kv.y;
                        acc[0][2] += x00 * kv.z; acc[0][3] += x00 * kv.w;
                        acc[1][0] += x01 * kv.x; acc[1][1] += x01 * kv.y;
                        acc[1][2] += x01 * kv.z; acc[1][3] += x01 * kv.w;
                        acc[2][0] += x10 * kv.x; acc[2][1] += x10 * kv.y;
                        acc[2][2] += x10 * kv.z; acc[2][3] += x10 * kv.w;
                        acc[3][0] += x11 * kv.x; acc[3][1] += x11 * kv.y;
                        acc[3][2] += x11 * kv.z; acc[3][3] += x11 * kv.w;
                    }
                }
            }
            r00 = frelu(fmaxf(fmaxf(acc[0][0], acc[1][0]), fmaxf(acc[2][0], acc[3][0])));
            r01 = frelu(fmaxf(fmaxf(acc[0][1], acc[1][1]), fmaxf(acc[2][1], acc[3][1])));
            r10 = frelu(fmaxf(fmaxf(acc[0][2], acc[1][2]), fmaxf(acc[2][2], acc[3][2])));
            r11 = frelu(fmaxf(fmaxf(acc[0][3], acc[1][3]), fmaxf(acc[2][3], acc[3][3])));
        }
        *(float4*)&p1[pos * 32 + ocg * 4] = make_float4(r00, r01, r10, r11);
    }
    __syncthreads();   // sync2 — p1 ready

    // ===== P2: conv2 partials (threads 256..511, k2 in registers) =========
    if (tid >= 256) {
        const int t   = tid - 256;
        const int ic  = t >> 3;
        const int ocg = t & 7;
        float acc[4][4];
#pragma unroll
        for (int q = 0; q < 4; ++q) { acc[q][0] = acc[q][1] = acc[q][2] = acc[q][3] = 0.f; }
#pragma unroll
        for (int dh = 0; dh < 5; ++dh)
#pragma unroll
            for (int dw = 0; dw < 5; ++dw) {
                const float4 kv = kreg[dh * 5 + dw];
                float pv[4];
#pragma unroll
                for (int pos = 0; pos < 4; ++pos) {
                    const int dy = pos >> 1, dx = pos & 1;
                    pv[pos] = p1[((dy + dh) * 6 + (dx + dw)) * 32 + ic];
                }
#pragma unroll
                for (int pos = 0; pos < 4; ++pos) {
                    acc[pos][0] += pv[pos] * kv.x;
                    acc[pos][1] += pv[pos] * kv.y;
                    acc[pos][2] += pv[pos] * kv.z;
                    acc[pos][3] += pv[pos] * kv.w;
                }
            }
#pragma unroll
        for (int pos = 0; pos < 4; ++pos)
#pragma unroll
            for (int o = 0; o < 4; ++o)
                part[ic * 132 + pos * 32 + ocg * 4 + o] = acc[pos][o];
    }
    __syncthreads();   // sync3

    // ===== P3: ic-reduce + bias + relu + pool2 (128 thr + shfl max) =======
    if (tid < 128) {
        const int oc  = tid >> 2;
        const int pos = tid & 3;         // shfl_xor partner stays in-wave
        float s = b2reg;
        for (int ic = 0; ic < 32; ++ic)
            s += part[ic * 132 + pos * 32 + oc];
        float v = frelu(s);
        v = fmaxf(v, __shfl_xor(v, 1));
        v = fmaxf(v, __shfl_xor(v, 2));
        if (pos == 0) zz[oc] = v;
    }
    __syncthreads();   // sync4

    // ===== P4: dense1 32->300 (register weights) ===========================
    if (tid < 300) {
        float acc = d1breg;
#pragma unroll
        for (int c = 0; c < 32; ++c)
            acc += zz[c] * rd1[c];
        aa[tid] = frelu(acc);
    }
    __syncthreads();   // sync5

    // ===== P5: dense2 (wave-per-channel reduce, weights in regs) ===========
    if (tid < 64 * nch) {
        const int wv = tid >> 6, lane = tid & 63;
        float s = 0.f;
#pragma unroll
        for (int u = 0; u < 5; ++u) {
            const int j = lane + 64 * u;
            if (j < 300) s += aa[j] * d2reg[u];
        }
        for (int off = 32; off > 0; off >>= 1)
            s += __shfl_down(s, off);
        if (lane == 0) yy[wv] = frelu(s + d2breg);
    }
    __syncthreads();   // sync6

    // ===== P6: heads (register weights) ====================================
    if (p < 32) {
        const float y1 = yy[0], y2 = yy[1], y3 = yy[2];
#pragma unroll
        for (int u = 0; u < 4; ++u) {
            const int i = tid + u * TPB;
            if (i < 2001) out[p * 2001 + i] = frelu(y1 * hk1[u] + hb1[u]);
        }
#pragma unroll
        for (int u = 0; u < 2; ++u) {
            const int i = tid + u * TPB;
            if (i < 801) out[64032 + p * 801 + i] = frelu(y2 * hk2[u] + hb2[u]);
        }
        if (tid < 321) out[89664 + p * 321 + tid] = frelu(y3 * hk3 + hb3);
    } else {
        const float y4 = yy[0];
        if (tid < 65) out[99936 + (p - 32) * 65 + tid] = frelu(y4 * hk4 + hb4);
    }
}

extern "C" void kernel_launch(void* const* d_in, const int* in_sizes, int n_in,
                              void* d_out, int out_size, void* d_ws, size_t ws_size,
                              hipStream_t stream) {
    (void)in_sizes; (void)n_in; (void)d_ws; (void)ws_size; (void)out_size;
    const float* x   = (const float*)d_in[0];
    const float* k1  = (const float*)d_in[1];
    const float* b1  = (const float*)d_in[2];
    const float* k2  = (const float*)d_in[3];
    const float* b2  = (const float*)d_in[4];
    const float* d1k = (const float*)d_in[5];
    const float* d1b = (const float*)d_in[6];
    const float* d2k = (const float*)d_in[7];
    const float* d2b = (const float*)d_in[8];
    const float* w1k = (const float*)d_in[9];
    const float* w1b = (const float*)d_in[10];
    const float* w2k = (const float*)d_in[11];
    const float* w2b = (const float*)d_in[12];
    const float* w3k = (const float*)d_in[13];
    const float* w3b = (const float*)d_in[14];
    const float* w4k = (const float*)d_in[15];
    const float* w4b = (const float*)d_in[16];

    hyper_kernel<<<38, TPB, 0, stream>>>(
        x, k1, b1, k2, b2, d1k, d1b, d2k, d2b,
        w1k, w1b, w2k, w2b, w3k, w3b, w4k, w4b,
        (float*)d_out);
}

// Round 6
// 14.237 us; speedup vs baseline: 2.3684x; 1.0445x over previous
//
#include <hip/hip_runtime.h>

#define TPB 512

__device__ __forceinline__ float frelu(float v) { return v > 0.f ? v : 0.f; }

// One block per needed output position (38 total).
// Blocks 0..31: (b=p>>2, h2=(p&3)*20, w2=0), d2 channels {1,161,321}.
// Blocks 32..37: head4 positions, single d2 channel.
//
//  P0: issue ALL global loads (regs + LDS), incl. k2 -> regs of thr 256-511
//  P1: conv1 (threads 0..287, COLUMN-MAJOR pos map: wave0 self-skips when
//      w2==0 since wp6 in {0,1} is out-of-range -> each SIMD issues exactly
//      one conv1 stream)
//  P2: conv2 partials (threads 256..511, k2 already in registers)
//  P3: ic-reduce + bias + relu + pool2 (threads 0..127 + shfl_xor max)
//  P4: dense1 32->300 (register weights)
//  P5: dense2 (wave-per-channel reduce, d2 weights in registers)
//  P6: heads (register weights)
__global__ __launch_bounds__(TPB, 1) void hyper_kernel(
    const float* __restrict__ x,    // (8,640,640,3)
    const float* __restrict__ k1,   // (5,5,3,32)
    const float* __restrict__ b1,   // (32)
    const float* __restrict__ k2,   // (5,5,32,32)
    const float* __restrict__ b2,   // (32)
    const float* __restrict__ d1k,  // (32,300)
    const float* __restrict__ d1b,  // (300)
    const float* __restrict__ d2k,  // (300,1340)
    const float* __restrict__ d2b,  // (1340)
    const float* __restrict__ w1k, const float* __restrict__ w1b,  // 2001
    const float* __restrict__ w2k, const float* __restrict__ w2b,  // 801
    const float* __restrict__ w3k, const float* __restrict__ w3b,  // 321
    const float* __restrict__ w4k, const float* __restrict__ w4b,  // 65
    float* __restrict__ out)        // 100326
{
    __shared__ float xs[3 * 676];        // channel-planar x patch [ic][26][26]
    __shared__ float k1s[2400];
    __shared__ float p1[36 * 32];
    __shared__ float part[32 * 132];     // [ic][pos*33 + oc]
    __shared__ float zz[32];
    __shared__ float aa[300];
    __shared__ float yy[3];

    const int p   = blockIdx.x;
    const int tid = threadIdx.x;

    int b, h2, w2, nch, ch0, ch1, ch2;
    if (p < 32) {
        b = p >> 2; h2 = (p & 3) * 20; w2 = 0;
        nch = 3; ch0 = 1; ch1 = 161; ch2 = 321;
    } else {
        const int qb[6] = {0, 1, 2, 4, 5, 6};
        const int qh[6] = {0, 26, 53, 0, 26, 53};
        const int qw[6] = {0, 53, 26, 0, 53, 26};
        const int qc[6] = {481, 491, 501, 481, 491, 501};
        const int q = p - 32;
        b = qb[q]; h2 = qh[q]; w2 = qw[q];
        nch = 1; ch0 = qc[q]; ch1 = 0; ch2 = 0;
    }

    // ================= P0: issue ALL independent global loads =============
    // dense1 weights+bias (thread j owns output j)
    float rd1[32];
    float d1breg = 0.f;
    if (tid < 300) {
#pragma unroll
        for (int c = 0; c < 32; ++c) rd1[c] = d1k[c * 300 + tid];
        d1breg = d1b[tid];
    }

    // conv1 bias (4 oc per conv1 thread)
    float4 b1reg = make_float4(0.f, 0.f, 0.f, 0.f);
    if (tid < 288) b1reg = *(const float4*)&b1[(tid & 7) * 4];

    // conv2 bias (P3 threads)
    float b2reg = (tid < 128) ? b2[tid >> 2] : 0.f;

    // dense2 gather columns + bias -> P5 thread registers
    float d2reg[5] = {0.f, 0.f, 0.f, 0.f, 0.f};
    float d2breg = 0.f;
    if (tid < 192) {
        const int wv = tid >> 6;
        if (wv < nch) {
            const int ch = (wv == 0) ? ch0 : ((wv == 1) ? ch1 : ch2);
#pragma unroll
            for (int u = 0; u < 5; ++u) {
                const int j = (tid & 63) + 64 * u;
                if (j < 300) d2reg[u] = d2k[j * 1340 + ch];
            }
            d2breg = d2b[ch];
        }
    }

    // k2 -> registers of the P2 threads (256..511): 25 float4 each
    float4 kreg[25];
    if (tid >= 256) {
        const int t = tid - 256;
        const float4* k2v = (const float4*)k2 + (t >> 3) * 8 + (t & 7);
#pragma unroll
        for (int tap = 0; tap < 25; ++tap) kreg[tap] = k2v[tap * 256];
    }

    // head weights/biases -> registers
    float hk1[4], hb1[4], hk2[2], hb2[2], hk3 = 0.f, hb3 = 0.f, hk4 = 0.f, hb4 = 0.f;
    if (p < 32) {
#pragma unroll
        for (int u = 0; u < 4; ++u) {
            const int i = tid + u * TPB;
            if (i < 2001) { hk1[u] = w1k[i]; hb1[u] = w1b[i]; }
        }
#pragma unroll
        for (int u = 0; u < 2; ++u) {
            const int i = tid + u * TPB;
            if (i < 801) { hk2[u] = w2k[i]; hb2[u] = w2b[i]; }
        }
        if (tid < 321) { hk3 = w3k[tid]; hb3 = w3b[tid]; }
    } else {
        if (tid < 65) { hk4 = w4k[tid]; hb4 = w4b[tid]; }
    }

    // x patch -> LDS, channel-planar (zero-padded)
    const int r0 = 8 * h2 - 10;
    const int c0 = 8 * w2 - 10;
    for (int idx = tid; idx < 3 * 676; idx += TPB) {
        const int ic  = idx / 676;
        const int rem = idx - ic * 676;
        const int row = rem / 26, col = rem - (rem / 26) * 26;
        const int gh = r0 + row, gw = c0 + col;
        float v = 0.f;
        if ((unsigned)gh < 640u && (unsigned)gw < 640u)
            v = x[((b * 640 + gh) * 640 + gw) * 3 + ic];
        xs[idx] = v;
    }
    for (int i = tid; i < 2400; i += TPB) k1s[i] = k1[i];
    __syncthreads();   // sync1 — one round trip for everything above

    // ===== P1: conv1 (threads 0..287, column-major pos, 4tap x 4oc) =======
    if (tid < 288) {
        const int posp = tid >> 3;       // 0..35, COLUMN-major
        const int ocg  = tid & 7;        // 4 oc per thread
        const int wp6 = posp / 6, hp6 = posp - wp6 * 6;
        const int pos = hp6 * 6 + wp6;   // canonical row-major index into p1
        const int hp = 2 * h2 - 2 + hp6;
        const int wp = 2 * w2 - 2 + wp6;
        float r00 = 0.f, r01 = 0.f, r10 = 0.f, r11 = 0.f;
        if ((unsigned)hp < 160u && (unsigned)wp < 160u) {
            float acc[4][4];
#pragma unroll
            for (int t4 = 0; t4 < 4; ++t4) {
                acc[t4][0] = b1reg.x; acc[t4][1] = b1reg.y;
                acc[t4][2] = b1reg.z; acc[t4][3] = b1reg.w;
            }
            const int rbase = 4 * hp6, cbase = 4 * wp6;
#pragma unroll
            for (int dh = 0; dh < 5; ++dh) {
#pragma unroll
                for (int ic = 0; ic < 3; ++ic) {
                    const float* rp0 = &xs[ic * 676 + (rbase + dh) * 26 + cbase];
                    const float2 a0 = *(const float2*)(rp0);
                    const float2 a2 = *(const float2*)(rp0 + 2);
                    const float2 a4 = *(const float2*)(rp0 + 4);
                    const float2 c0_ = *(const float2*)(rp0 + 26);
                    const float2 c2_ = *(const float2*)(rp0 + 28);
                    const float2 c4_ = *(const float2*)(rp0 + 30);
                    const float xr0[6] = {a0.x, a0.y, a2.x, a2.y, a4.x, a4.y};
                    const float xr1[6] = {c0_.x, c0_.y, c2_.x, c2_.y, c4_.x, c4_.y};
#pragma unroll
                    for (int dw = 0; dw < 5; ++dw) {
                        const float4 kv = *(const float4*)&k1s[(((dh * 5 + dw) * 3 + ic) << 5) + (ocg << 2)];
                        const float x00 = xr0[dw], x01 = xr0[dw + 1];
                        const float x10 = xr1[dw], x11 = xr1[dw + 1];
                        acc[0][0] += x00 * kv.x; acc[0][1] += x00 * kv.y;
                        acc[0][2] += x00 * kv.z; acc[0][3] += x00 * kv.w;
                        acc[1][0] += x01 * kv.x; acc[1][1] += x01 * kv.y;
                        acc[1][2] += x01 * kv.z; acc[1][3] += x01 * kv.w;
                        acc[2][0] += x10 * kv.x; acc[2][1] += x10 * kv.y;
                        acc[2][2] += x10 * kv.z; acc[2][3] += x10 * kv.w;
                        acc[3][0] += x11 * kv.x; acc[3][1] += x11 * kv.y;
                        acc[3][2] += x11 * kv.z; acc[3][3] += x11 * kv.w;
                    }
                }
            }
            r00 = frelu(fmaxf(fmaxf(acc[0][0], acc[1][0]), fmaxf(acc[2][0], acc[3][0])));
            r01 = frelu(fmaxf(fmaxf(acc[0][1], acc[1][1]), fmaxf(acc[2][1], acc[3][1])));
            r10 = frelu(fmaxf(fmaxf(acc[0][2], acc[1][2]), fmaxf(acc[2][2], acc[3][2])));
            r11 = frelu(fmaxf(fmaxf(acc[0][3], acc[1][3]), fmaxf(acc[2][3], acc[3][3])));
        }
        *(float4*)&p1[pos * 32 + ocg * 4] = make_float4(r00, r01, r10, r11);
    }
    __syncthreads();   // sync2 — p1 ready

    // ===== P2: conv2 partials (threads 256..511, k2 in registers) =========
    if (tid >= 256) {
        const int t   = tid - 256;
        const int ic  = t >> 3;
        const int ocg = t & 7;
        float acc[4][4];
#pragma unroll
        for (int q = 0; q < 4; ++q) { acc[q][0] = acc[q][1] = acc[q][2] = acc[q][3] = 0.f; }
#pragma unroll
        for (int dh = 0; dh < 5; ++dh)
#pragma unroll
            for (int dw = 0; dw < 5; ++dw) {
                const float4 kv = kreg[dh * 5 + dw];
                float pv[4];
#pragma unroll
                for (int pos = 0; pos < 4; ++pos) {
                    const int dy = pos >> 1, dx = pos & 1;
                    pv[pos] = p1[((dy + dh) * 6 + (dx + dw)) * 32 + ic];
                }
#pragma unroll
                for (int pos = 0; pos < 4; ++pos) {
                    acc[pos][0] += pv[pos] * kv.x;
                    acc[pos][1] += pv[pos] * kv.y;
                    acc[pos][2] += pv[pos] * kv.z;
                    acc[pos][3] += pv[pos] * kv.w;
                }
            }
#pragma unroll
        for (int pos = 0; pos < 4; ++pos)
#pragma unroll
            for (int o = 0; o < 4; ++o)
                part[ic * 132 + pos * 33 + ocg * 4 + o] = acc[pos][o];
    }
    __syncthreads();   // sync3

    // ===== P3: ic-reduce + bias + relu + pool2 (128 thr + shfl max) =======
    if (tid < 128) {
        const int oc  = tid >> 2;
        const int pos = tid & 3;         // shfl_xor partner stays in-wave
        float s = b2reg;
        for (int ic = 0; ic < 32; ++ic)
            s += part[ic * 132 + pos * 33 + oc];
        float v = frelu(s);
        v = fmaxf(v, __shfl_xor(v, 1));
        v = fmaxf(v, __shfl_xor(v, 2));
        if (pos == 0) zz[oc] = v;
    }
    __syncthreads();   // sync4

    // ===== P4: dense1 32->300 (register weights) ===========================
    if (tid < 300) {
        float acc = d1breg;
#pragma unroll
        for (int c = 0; c < 32; ++c)
            acc += zz[c] * rd1[c];
        aa[tid] = frelu(acc);
    }
    __syncthreads();   // sync5

    // ===== P5: dense2 (wave-per-channel reduce, weights in regs) ===========
    if (tid < 64 * nch) {
        const int wv = tid >> 6, lane = tid & 63;
        float s = 0.f;
#pragma unroll
        for (int u = 0; u < 5; ++u) {
            const int j = lane + 64 * u;
            if (j < 300) s += aa[j] * d2reg[u];
        }
        for (int off = 32; off > 0; off >>= 1)
            s += __shfl_down(s, off);
        if (lane == 0) yy[wv] = frelu(s + d2breg);
    }
    __syncthreads();   // sync6

    // ===== P6: heads (register weights) ====================================
    if (p < 32) {
        const float y1 = yy[0], y2 = yy[1], y3 = yy[2];
#pragma unroll
        for (int u = 0; u < 4; ++u) {
            const int i = tid + u * TPB;
            if (i < 2001) out[p * 2001 + i] = frelu(y1 * hk1[u] + hb1[u]);
        }
#pragma unroll
        for (int u = 0; u < 2; ++u) {
            const int i = tid + u * TPB;
            if (i < 801) out[64032 + p * 801 + i] = frelu(y2 * hk2[u] + hb2[u]);
        }
        if (tid < 321) out[89664 + p * 321 + tid] = frelu(y3 * hk3 + hb3);
    } else {
        const float y4 = yy[0];
        if (tid < 65) out[99936 + (p - 32) * 65 + tid] = frelu(y4 * hk4 + hb4);
    }
}

extern "C" void kernel_launch(void* const* d_in, const int* in_sizes, int n_in,
                              void* d_out, int out_size, void* d_ws, size_t ws_size,
                              hipStream_t stream) {
    (void)in_sizes; (void)n_in; (void)d_ws; (void)ws_size; (void)out_size;
    const float* x   = (const float*)d_in[0];
    const float* k1  = (const float*)d_in[1];
    const float* b1  = (const float*)d_in[2];
    const float* k2  = (const float*)d_in[3];
    const float* b2  = (const float*)d_in[4];
    const float* d1k = (const float*)d_in[5];
    const float* d1b = (const float*)d_in[6];
    const float* d2k = (const float*)d_in[7];
    const float* d2b = (const float*)d_in[8];
    const float* w1k = (const float*)d_in[9];
    const float* w1b = (const float*)d_in[10];
    const float* w2k = (const float*)d_in[11];
    const float* w2b = (const float*)d_in[12];
    const float* w3k = (const float*)d_in[13];
    const float* w3b = (const float*)d_in[14];
    const float* w4k = (const float*)d_in[15];
    const float* w4b = (const float*)d_in[16];

    hyper_kernel<<<38, TPB, 0, stream>>>(
        x, k1, b1, k2, b2, d1k, d1b, d2k, d2b,
        w1k, w1b, w2k, w2b, w3k, w3b, w4k, w4b,
        (float*)d_out);
}